// Round 10
// baseline (220.997 us; speedup 1.0000x reference)
//
#include <hip/hip_runtime.h>
#include <hip/hip_bf16.h>

#define BS    128
#define NCIN  64
#define NCOUT 64
#define LLEN  8192
#define NK    3
#define NR    8
#define NEMB  256
#define NHID  256
#define WPS   (NCOUT * NCIN * NK)   // 12288 weights per sample
#define NT    128                   // l-positions per conv tile/block

typedef __attribute__((ext_vector_type(4)))  float  f32x4;
typedef __attribute__((ext_vector_type(16))) float  f32x16;
typedef __attribute__((ext_vector_type(4)))  __bf16 bf16x4;
typedef __attribute__((ext_vector_type(8)))  __bf16 bf16x8;

// Static device scratch (fully rewritten every call).
__device__ float  g_A[BS * 512];    // A factors [b][ci*8+r]
__device__ float  g_B[BS * 1536];   // B factors [b][r*192+co*3+k]
__device__ __bf16 g_Wb[BS * WPS];   // W_eff bf16 [b][k*4096+co*64+ci]

// ---------------------------------------------------------------------------
// Kernel 1: MLP branches (hidden + outputs fused). 256 blocks = (branch, sample).
// ---------------------------------------------------------------------------
__global__ __launch_bounds__(256) void mlp_kernel(
    const float* __restrict__ a_emb, const float* __restrict__ b_emb,
    const float* __restrict__ A_w1, const float* __restrict__ A_b1,
    const float* __restrict__ A_g,  const float* __restrict__ A_beta,
    const float* __restrict__ A_w2, const float* __restrict__ A_b2,
    const float* __restrict__ B_w1, const float* __restrict__ B_b1,
    const float* __restrict__ B_g,  const float* __restrict__ B_beta,
    const float* __restrict__ B_w2, const float* __restrict__ B_b2)
{
    __shared__ __align__(16) float emb_s[NEMB];
    __shared__ __align__(16) float h_s[NHID];

    const int t      = threadIdx.x;
    const int branch = blockIdx.x >> 7;
    const int b      = blockIdx.x & 127;

    const float* emb  = (branch ? b_emb : a_emb) + (size_t)b * NEMB;
    const float* w1   = branch ? B_w1 : A_w1;
    const float* b1   = branch ? B_b1 : A_b1;
    const float* gg   = branch ? B_g  : A_g;
    const float* bt   = branch ? B_beta : A_beta;
    const float* w2   = branch ? B_w2 : A_w2;
    const float* b2   = branch ? B_b2 : A_b2;
    float* outp       = (branch ? g_B : g_A) + (size_t)b * (branch ? 1536 : 512);
    const int nloops  = branch ? 6 : 2;

    emb_s[t] = emb[t];
    __syncthreads();

    // hidden: Linear + BN(eval, mean=0 var=1) + exact GELU
    {
        float acc = b1[t];
        const f32x4* wr = (const f32x4*)(w1 + (size_t)t * NEMB);
        const f32x4* es = (const f32x4*)emb_s;
        for (int e = 0; e < NEMB / 4; ++e) {
            f32x4 w = wr[e], a = es[e];
            acc += w[0]*a[0] + w[1]*a[1] + w[2]*a[2] + w[3]*a[3];
        }
        float h = acc * (gg[t] * (1.0f / sqrtf(1.0f + 1e-5f))) + bt[t];
        h = 0.5f * h * (1.0f + erff(h * 0.70710678118654752f));
        h_s[t] = h;
    }
    __syncthreads();

    // outputs
    for (int oo = 0; oo < nloops; ++oo) {
        const int o = oo * 256 + t;
        float acc = b2[o];
        const f32x4* wr = (const f32x4*)(w2 + (size_t)o * NHID);
        const f32x4* hs = (const f32x4*)h_s;
        for (int e = 0; e < NHID / 4; ++e) {
            f32x4 w = wr[e], h = hs[e];
            acc += w[0]*h[0] + w[1]*h[1] + w[2]*h[2] + w[3]*h[3];
        }
        outp[o] = acc;
    }
}

// ---------------------------------------------------------------------------
// Kernel 2: assemble W_eff = base_w + A·B  (bf16, [b][k*4096+co*64+ci]).
// ---------------------------------------------------------------------------
__global__ __launch_bounds__(256) void assemble_kernel(const float* __restrict__ base_w)
{
    const int b  = blockIdx.x >> 2;
    const int q  = blockIdx.x & 3;
    const int t  = threadIdx.x;
    const int ci = t & 63;

    float Ar[NR];
    const f32x4* Ap = (const f32x4*)(g_A + (size_t)b * 512 + ci * NR);
    f32x4 a0 = Ap[0], a1 = Ap[1];
    Ar[0]=a0[0]; Ar[1]=a0[1]; Ar[2]=a0[2]; Ar[3]=a0[3];
    Ar[4]=a1[0]; Ar[5]=a1[1]; Ar[6]=a1[2]; Ar[7]=a1[3];

    const float* Bp = g_B + (size_t)b * 1536;
    for (int i = 0; i < 12; ++i) {
        const int w  = q * 3072 + i * 256 + t;
        const int k  = w >> 12;
        const int co = (w >> 6) & 63;
        float v = base_w[(size_t)(co * 64 + ci) * 3 + k];
        #pragma unroll
        for (int r = 0; r < NR; ++r) v += Ar[r] * Bp[r * 192 + co * 3 + k];
        g_Wb[(size_t)b * WPS + w] = (__bf16)v;
    }
}

// ---------------------------------------------------------------------------
// Kernel 3: conv as MFMA GEMM, small tiles for max occupancy.
// 8192 blocks = (b, 128-l tile), XCD-swizzled. LDS = 16.6 KB -> 8 blocks/CU,
// 32 waves/CU. One barrier. Direct full-line stores.
// LDS: [lp][ci] bf16, lp 0..129, blk-swizzle (ci>>3)^(lp&7)^((lp>>3)&7).
// Per wave: 32 co (wco) x 64 l (wl); 24 MFMA 32x32x16, 24 ds_read_b128.
// ---------------------------------------------------------------------------
__global__ __launch_bounds__(256, 4) void conv_kernel(
    const float* __restrict__ X, const float* __restrict__ base_b,
    float* __restrict__ out)
{
    __shared__ __align__(16) __bf16 xt[(NT + 2) * 64];   // 16640 B

    // bijective XCD swizzle: XCD x owns contiguous block range
    const int swz  = (blockIdx.x & 7) * 1024 + (blockIdx.x >> 3);
    const int b    = swz >> 6;            // 64 tiles per sample
    const int tile = swz & 63;
    const int l0   = tile * NT;

    const int t     = threadIdx.x;
    const int lane  = t & 63;
    const int wave  = t >> 6;
    const int l31   = lane & 31;
    const int khalf = lane >> 5;
    const int wco   = wave >> 1;          // which 32 co
    const int wl    = wave & 1;           // which 64 l
    const int lb    = t & 15;             // staging: 8-l block
    const int cb    = t >> 4;             // staging: 4-ci block

    const float* xbase = X + (size_t)b * NCIN * LLEN;

    // ---- stage X tile: 4ci x 8l micro-tile per thread ----
    {
        f32x4 v[4][2];
        const float* xb = xbase + l0 + lb * 8;
        #pragma unroll
        for (int c = 0; c < 4; ++c) {
            const float* xr = xb + (size_t)(cb * 4 + c) * LLEN;
            v[c][0] = *(const f32x4*)(xr);
            v[c][1] = *(const f32x4*)(xr + 4);
        }
        #pragma unroll
        for (int j = 0; j < 8; ++j) {
            const int lp = lb * 8 + j + 1;
            bf16x4 w;
            #pragma unroll
            for (int c = 0; c < 4; ++c) w[c] = (__bf16)v[c][j >> 2][j & 3];
            const int blk = (cb >> 1) ^ (lp & 7) ^ ((lp >> 3) & 7);
            *(bf16x4*)(xt + lp * 64 + blk * 8 + (cb & 1) * 4) = w;
        }
        if (t < 128) {  // halo columns (pad = 1)
            const int ci    = t & 63;
            const int right = t >> 6;
            const int gl    = right ? (l0 + NT) : (l0 - 1);
            const int lp    = right ? (NT + 1) : 0;
            const float hv  = (gl >= 0 && gl < LLEN) ? xbase[(size_t)ci * LLEN + gl] : 0.0f;
            const int blk   = (ci >> 3) ^ (lp & 7) ^ ((lp >> 3) & 7);
            xt[lp * 64 + blk * 8 + (ci & 7)] = (__bf16)hv;
        }
    }
    __syncthreads();

    // ---- W fragments (after staging: v regs dead -> lower peak VGPR) ----
    bf16x8 af[3][4];
    {
        const __bf16* wb = g_Wb + (size_t)b * WPS + (wco * 32 + l31) * 64 + khalf * 8;
        #pragma unroll
        for (int tap = 0; tap < 3; ++tap)
            #pragma unroll
            for (int c16 = 0; c16 < 4; ++c16)
                af[tap][c16] = *(const bf16x8*)(wb + tap * 4096 + c16 * 16);
    }

    // ---- MFMA: 2 l-subtiles x (3 taps x 4 ci16) ----
    f32x16 acc[2] = {};
    #pragma unroll
    for (int tap = 0; tap < 3; ++tap)
        #pragma unroll
        for (int c16 = 0; c16 < 4; ++c16)
            #pragma unroll
            for (int n = 0; n < 2; ++n) {
                const int R   = wl * 64 + n * 32 + l31 + tap;
                const int blk = (c16 * 2 + khalf) ^ (R & 7) ^ ((R >> 3) & 7);
                bf16x8 bfr = *(const bf16x8*)(xt + R * 64 + blk * 8);
                acc[n] = __builtin_amdgcn_mfma_f32_32x32x16_bf16(af[tap][c16], bfr, acc[n], 0, 0, 0);
            }

    // ---- epilogue: + base_b, direct stores (2 x 128 B full lines per instr) ----
    #pragma unroll
    for (int reg = 0; reg < 16; ++reg) {
        const int col = (reg & 3) + 8 * (reg >> 2) + 4 * khalf;  // co_local
        const int co  = wco * 32 + col;
        const float bb = base_b[co];
        float* op = out + (size_t)(b * NCOUT + co) * LLEN + l0 + wl * 64 + l31;
        #pragma unroll
        for (int n = 0; n < 2; ++n)
            op[n * 32] = acc[n][reg] + bb;
    }
}

// ---------------------------------------------------------------------------
extern "C" void kernel_launch(void* const* d_in, const int* in_sizes, int n_in,
                              void* d_out, int out_size, void* d_ws, size_t ws_size,
                              hipStream_t stream)
{
    const float* X      = (const float*)d_in[0];
    const float* a_emb  = (const float*)d_in[1];
    const float* b_emb  = (const float*)d_in[2];
    const float* A_w1   = (const float*)d_in[3];
    const float* A_b1   = (const float*)d_in[4];
    const float* A_g    = (const float*)d_in[5];
    const float* A_beta = (const float*)d_in[6];
    const float* A_w2   = (const float*)d_in[7];
    const float* A_b2   = (const float*)d_in[8];
    const float* B_w1   = (const float*)d_in[9];
    const float* B_b1   = (const float*)d_in[10];
    const float* B_g    = (const float*)d_in[11];
    const float* B_beta = (const float*)d_in[12];
    const float* B_w2   = (const float*)d_in[13];
    const float* B_b2   = (const float*)d_in[14];
    const float* base_w = (const float*)d_in[15];
    const float* base_b = (const float*)d_in[16];

    float* out = (float*)d_out;   // reference output dtype is float32

    mlp_kernel<<<2 * BS, 256, 0, stream>>>(a_emb, b_emb,
        A_w1, A_b1, A_g, A_beta, A_w2, A_b2,
        B_w1, B_b1, B_g, B_beta, B_w2, B_b2);

    assemble_kernel<<<4 * BS, 256, 0, stream>>>(base_w);

    conv_kernel<<<8192, 256, 0, stream>>>(X, base_b, out);
}

// Round 11
// 188.651 us; speedup vs baseline: 1.1715x; 1.1715x over previous
//
#include <hip/hip_runtime.h>
#include <hip/hip_bf16.h>

#define BS    128
#define NCIN  64
#define NCOUT 64
#define LLEN  8192
#define NK    3
#define NR    8
#define NEMB  256
#define NHID  256
#define WPS   (NCOUT * NCIN * NK)   // 12288 weights per sample
#define NT    512                   // l-positions per conv tile/block (2 KB chunks)

typedef __attribute__((ext_vector_type(4)))  float  f32x4;
typedef __attribute__((ext_vector_type(16))) float  f32x16;
typedef __attribute__((ext_vector_type(8)))  __bf16 bf16x8;

// Static device scratch (fully rewritten every call).
__device__ float  g_A[BS * 512];    // A factors [b][ci*8+r]
__device__ float  g_B[BS * 1536];   // B factors [b][r*192+co*3+k]
__device__ __bf16 g_Wb[BS * WPS];   // W_eff bf16 [b][k*4096+co*64+ci]

// ---------------------------------------------------------------------------
// Kernel 1: MLP branches (hidden + outputs fused). 256 blocks = (branch, sample).
// ---------------------------------------------------------------------------
__global__ __launch_bounds__(256) void mlp_kernel(
    const float* __restrict__ a_emb, const float* __restrict__ b_emb,
    const float* __restrict__ A_w1, const float* __restrict__ A_b1,
    const float* __restrict__ A_g,  const float* __restrict__ A_beta,
    const float* __restrict__ A_w2, const float* __restrict__ A_b2,
    const float* __restrict__ B_w1, const float* __restrict__ B_b1,
    const float* __restrict__ B_g,  const float* __restrict__ B_beta,
    const float* __restrict__ B_w2, const float* __restrict__ B_b2)
{
    __shared__ __align__(16) float emb_s[NEMB];
    __shared__ __align__(16) float h_s[NHID];

    const int t      = threadIdx.x;
    const int branch = blockIdx.x >> 7;
    const int b      = blockIdx.x & 127;

    const float* emb  = (branch ? b_emb : a_emb) + (size_t)b * NEMB;
    const float* w1   = branch ? B_w1 : A_w1;
    const float* b1   = branch ? B_b1 : A_b1;
    const float* gg   = branch ? B_g  : A_g;
    const float* bt   = branch ? B_beta : A_beta;
    const float* w2   = branch ? B_w2 : A_w2;
    const float* b2   = branch ? B_b2 : A_b2;
    float* outp       = (branch ? g_B : g_A) + (size_t)b * (branch ? 1536 : 512);
    const int nloops  = branch ? 6 : 2;

    emb_s[t] = emb[t];
    __syncthreads();

    // hidden: Linear + BN(eval, mean=0 var=1) + exact GELU
    {
        float acc = b1[t];
        const f32x4* wr = (const f32x4*)(w1 + (size_t)t * NEMB);
        const f32x4* es = (const f32x4*)emb_s;
        for (int e = 0; e < NEMB / 4; ++e) {
            f32x4 w = wr[e], a = es[e];
            acc += w[0]*a[0] + w[1]*a[1] + w[2]*a[2] + w[3]*a[3];
        }
        float h = acc * (gg[t] * (1.0f / sqrtf(1.0f + 1e-5f))) + bt[t];
        h = 0.5f * h * (1.0f + erff(h * 0.70710678118654752f));
        h_s[t] = h;
    }
    __syncthreads();

    // outputs
    for (int oo = 0; oo < nloops; ++oo) {
        const int o = oo * 256 + t;
        float acc = b2[o];
        const f32x4* wr = (const f32x4*)(w2 + (size_t)o * NHID);
        const f32x4* hs = (const f32x4*)h_s;
        for (int e = 0; e < NHID / 4; ++e) {
            f32x4 w = wr[e], h = hs[e];
            acc += w[0]*h[0] + w[1]*h[1] + w[2]*h[2] + w[3]*h[3];
        }
        outp[o] = acc;
    }
}

// ---------------------------------------------------------------------------
// Kernel 2: assemble W_eff = base_w + A·B  (bf16, [b][k*4096+co*64+ci]).
// ---------------------------------------------------------------------------
__global__ __launch_bounds__(256) void assemble_kernel(const float* __restrict__ base_w)
{
    const int b  = blockIdx.x >> 2;
    const int q  = blockIdx.x & 3;
    const int t  = threadIdx.x;
    const int ci = t & 63;

    float Ar[NR];
    const f32x4* Ap = (const f32x4*)(g_A + (size_t)b * 512 + ci * NR);
    f32x4 a0 = Ap[0], a1 = Ap[1];
    Ar[0]=a0[0]; Ar[1]=a0[1]; Ar[2]=a0[2]; Ar[3]=a0[3];
    Ar[4]=a1[0]; Ar[5]=a1[1]; Ar[6]=a1[2]; Ar[7]=a1[3];

    const float* Bp = g_B + (size_t)b * 1536;
    for (int i = 0; i < 12; ++i) {
        const int w  = q * 3072 + i * 256 + t;
        const int k  = w >> 12;
        const int co = (w >> 6) & 63;
        float v = base_w[(size_t)(co * 64 + ci) * 3 + k];
        #pragma unroll
        for (int r = 0; r < NR; ++r) v += Ar[r] * Bp[r * 192 + co * 3 + k];
        g_Wb[(size_t)b * WPS + w] = (__bf16)v;
    }
}

// ---------------------------------------------------------------------------
// Kernel 3: conv as MFMA GEMM, NT=512 tiles (2 KB per-row DRAM chunks).
// 2048 blocks = (b, 512-l tile), XCD-swizzled. LDS 65.8 KB -> 2 blocks/CU.
// LDS: [lp][ci] bf16, lp 0..513, blk-swizzle (ci>>3)^(lp&7)^((lp>>3)&7).
// Per wave: 32 co (wco) x 256 l (wl); 96 MFMA 32x32x16, 96 ds_read_b128.
// ---------------------------------------------------------------------------
__global__ __launch_bounds__(256, 2) void conv_kernel(
    const float* __restrict__ X, const float* __restrict__ base_b,
    float* __restrict__ out)
{
    __shared__ __align__(16) __bf16 xt[(NT + 2) * 64];   // 65792 B

    // bijective XCD swizzle: each XCD owns a contiguous range of 256 tiles
    const int swz  = (blockIdx.x & 7) * 256 + (blockIdx.x >> 3);
    const int b    = swz >> 4;            // 16 tiles per sample
    const int tile = swz & 15;
    const int l0   = tile * NT;

    const int t     = threadIdx.x;
    const int lane  = t & 63;
    const int wave  = t >> 6;
    const int l31   = lane & 31;
    const int khalf = lane >> 5;
    const int wco   = wave >> 1;          // which 32 co
    const int wl    = wave & 1;           // which 256 l
    const int lb    = t & 63;             // staging: 8-l block (0..63)
    const int ch    = t >> 6;             // staging: base ci-octet (0..3)

    const float* xbase = X + (size_t)b * NCIN * LLEN;

    // ---- stage X tile: two passes of 8ci x 8l micro-tiles (conflict-free b128) ----
    #pragma unroll
    for (int pass = 0; pass < 2; ++pass) {
        const int och = ch + pass * 4;    // ci-octet 0..7
        f32x4 v[8][2];
        const float* xb = xbase + l0 + lb * 8;
        #pragma unroll
        for (int c = 0; c < 8; ++c) {
            const float* xr = xb + (size_t)(och * 8 + c) * LLEN;
            v[c][0] = *(const f32x4*)(xr);
            v[c][1] = *(const f32x4*)(xr + 4);
        }
        #pragma unroll
        for (int j = 0; j < 8; ++j) {
            const int lp = lb * 8 + j + 1;        // 1..512
            bf16x8 w;
            #pragma unroll
            for (int c = 0; c < 8; ++c) w[c] = (__bf16)v[c][j >> 2][j & 3];
            const int blk = och ^ (lp & 7) ^ ((lp >> 3) & 7);
            *(bf16x8*)(xt + lp * 64 + blk * 8) = w;
        }
    }
    if (t < 128) {  // halo columns (pad = 1)
        const int ci    = t & 63;
        const int right = t >> 6;
        const int gl    = right ? (l0 + NT) : (l0 - 1);
        const int lp    = right ? (NT + 1) : 0;
        const float hv  = (gl >= 0 && gl < LLEN) ? xbase[(size_t)ci * LLEN + gl] : 0.0f;
        const int blk   = (ci >> 3) ^ (lp & 7) ^ ((lp >> 3) & 7);
        xt[lp * 64 + blk * 8 + (ci & 7)] = (__bf16)hv;
    }
    __syncthreads();

    // ---- W fragments ----
    bf16x8 af[3][4];
    {
        const __bf16* wb = g_Wb + (size_t)b * WPS + (wco * 32 + l31) * 64 + khalf * 8;
        #pragma unroll
        for (int tap = 0; tap < 3; ++tap)
            #pragma unroll
            for (int c16 = 0; c16 < 4; ++c16)
                af[tap][c16] = *(const bf16x8*)(wb + tap * 4096 + c16 * 16);
    }

    // ---- MFMA: 8 l-subtiles x (3 taps x 4 ci16) ----
    f32x16 acc[8] = {};
    #pragma unroll
    for (int tap = 0; tap < 3; ++tap)
        #pragma unroll
        for (int c16 = 0; c16 < 4; ++c16)
            #pragma unroll
            for (int n = 0; n < 8; ++n) {
                const int R   = wl * 256 + n * 32 + l31 + tap;
                const int blk = (c16 * 2 + khalf) ^ (R & 7) ^ ((R >> 3) & 7);
                bf16x8 bfr = *(const bf16x8*)(xt + R * 64 + blk * 8);
                acc[n] = __builtin_amdgcn_mfma_f32_32x32x16_bf16(af[tap][c16], bfr, acc[n], 0, 0, 0);
            }

    // ---- epilogue: + base_b, direct stores (2 x 128 B full lines per instr) ----
    #pragma unroll
    for (int reg = 0; reg < 16; ++reg) {
        const int col = (reg & 3) + 8 * (reg >> 2) + 4 * khalf;  // co_local
        const int co  = wco * 32 + col;
        const float bb = base_b[co];
        float* op = out + (size_t)(b * NCOUT + co) * LLEN + l0 + wl * 256 + l31;
        #pragma unroll
        for (int n = 0; n < 8; ++n)
            op[n * 32] = acc[n][reg] + bb;
    }
}

// ---------------------------------------------------------------------------
extern "C" void kernel_launch(void* const* d_in, const int* in_sizes, int n_in,
                              void* d_out, int out_size, void* d_ws, size_t ws_size,
                              hipStream_t stream)
{
    const float* X      = (const float*)d_in[0];
    const float* a_emb  = (const float*)d_in[1];
    const float* b_emb  = (const float*)d_in[2];
    const float* A_w1   = (const float*)d_in[3];
    const float* A_b1   = (const float*)d_in[4];
    const float* A_g    = (const float*)d_in[5];
    const float* A_beta = (const float*)d_in[6];
    const float* A_w2   = (const float*)d_in[7];
    const float* A_b2   = (const float*)d_in[8];
    const float* B_w1   = (const float*)d_in[9];
    const float* B_b1   = (const float*)d_in[10];
    const float* B_g    = (const float*)d_in[11];
    const float* B_beta = (const float*)d_in[12];
    const float* B_w2   = (const float*)d_in[13];
    const float* B_b2   = (const float*)d_in[14];
    const float* base_w = (const float*)d_in[15];
    const float* base_b = (const float*)d_in[16];

    float* out = (float*)d_out;   // reference output dtype is float32

    mlp_kernel<<<2 * BS, 256, 0, stream>>>(a_emb, b_emb,
        A_w1, A_b1, A_g, A_beta, A_w2, A_b2,
        B_w1, B_b1, B_g, B_beta, B_w2, B_b2);

    assemble_kernel<<<4 * BS, 256, 0, stream>>>(base_w);

    conv_kernel<<<2048, 256, 0, stream>>>(X, base_b, out);
}